// Round 3
// baseline (143.200 us; speedup 1.0000x reference)
//
#include <hip/hip_runtime.h>

typedef __attribute__((ext_vector_type(4))) float f32x4;
typedef __attribute__((ext_vector_type(8))) __bf16 bf16x8;
typedef __attribute__((ext_vector_type(4))) __bf16 bf16x4;
typedef __attribute__((ext_vector_type(2))) unsigned int u32x2;

__device__ __forceinline__ u32x2 tr_read(unsigned int byte_addr){
    u32x2 d;
    asm volatile("ds_read_b64_tr_b16 %0, %1" : "=v"(d) : "v"(byte_addr));
    return d;
}
__device__ __forceinline__ bf16x8 frag_cat(u32x2 a, u32x2 b){
    union { u32x2 u[2]; bf16x8 f; } c; c.u[0] = a; c.u[1] = b; return c.f;
}

// ---------------------------------------------------------------------------
// Kernel A: x1 = x@prev_w+prev_b ; q/k/v = x1@{q,k,v}_w ; pos passthrough out
// ---------------------------------------------------------------------------
__global__ void ptb_precompute(const float* __restrict__ x,
                               const float* __restrict__ pos,
                               const float* __restrict__ prev_w,
                               const float* __restrict__ prev_b,
                               const float* __restrict__ q_w,
                               const float* __restrict__ k_w,
                               const float* __restrict__ v_w,
                               float* __restrict__ ws,
                               float* __restrict__ out)
{
    const int row = blockIdx.x;
    const int d   = threadIdx.x;
    __shared__ float xr[64], x1r[64];
    xr[d] = x[row*64 + d];
    __syncthreads();
    float a = prev_b[d];
    #pragma unroll 16
    for (int c = 0; c < 64; ++c) a += xr[c] * prev_w[c*64 + d];
    x1r[d] = a;
    ws[row*64 + d] = a;
    __syncthreads();
    float qv = 0.f, kv = 0.f, vv = 0.f;
    #pragma unroll 16
    for (int c = 0; c < 64; ++c){
        float t = x1r[c];
        qv += t * q_w[c*64 + d];
        kv += t * k_w[c*64 + d];
        vv += t * v_w[c*64 + d];
    }
    ws[ 65536 + row*64 + d] = qv;
    ws[131072 + row*64 + d] = kv;
    ws[196608 + row*64 + d] = vv;
    const int gid = row*64 + d;
    if (gid < 2*512*3) out[65536 + gid] = pos[gid];
}

// ---------------------------------------------------------------------------
// Kernel B: one block per (b,i). 4 waves. 64-j tiles.
// Software-pipelined schedule (convoy-breaking, round-3):
//   A(0) ; loop t: { B1 ; A(t+1) hoisted ; B(t) ; B2 ; C(t) }
// A(t+1) after B1(t) is safe: B1 guarantees no wave is still in C(t-1),
// the only reader of sTT[buf^1]. Counted lgkmcnt waits in B and C
// (DS completes in-order); s_setprio around MFMA clusters.
// NO launch-bounds min-waves pin (round-1: forced VGPR 84 + spills).
// ---------------------------------------------------------------------------
__global__ __launch_bounds__(256) void ptb_main(
    const float* __restrict__ pos,
    const float* __restrict__ pos_w1, const float* __restrict__ pos_b1,
    const float* __restrict__ pos_w2, const float* __restrict__ pos_b2,
    const float* __restrict__ attn_w1, const float* __restrict__ attn_b1,
    const float* __restrict__ attn_w2, const float* __restrict__ attn_b2,
    const float* __restrict__ fin_w, const float* __restrict__ fin_b,
    const float* __restrict__ ws, float* __restrict__ out)
{
    const int blk = blockIdx.x;
    const int b   = blk >> 9;
    const int i   = blk & 511;
    const int tid = threadIdx.x;
    const int w   = tid >> 6;
    const int l   = tid & 63;
    const int lg  = l >> 4;
    const int ln  = l & 15;

    // T^T tile, subtiled for tr_read: [buf][es=t/4][jt][er=t&3][jl] bf16
    __shared__ __bf16 sTT[2][16][4][4][16];      // 16 KB
    // H^T tile: [es=e/4][jt][er][jl]
    __shared__ __bf16 sHT[64][4][4][16];         // 32 KB
    __shared__ float sPW1[192], sPB1[64], sX1[64], sAGG[64], sPOSI[3];

    const float* x1p = ws;
    const float* qp  = ws + 65536;
    const float* kp  = ws + 131072;
    const float* vp  = ws + 196608;

    if (tid < 64){
        sX1[tid]  = x1p[blk*64 + tid];
        sPB1[tid] = pos_b1[tid];
    }
    if (tid >= 64 && tid < 256) sPW1[tid - 64] = pos_w1[tid - 64];
    if (tid < 3) sPOSI[tid] = pos[(b*512 + i)*3 + tid];

    const int dch = w*16 + ln;          // this lane's output channel (GEMM2)
    const int Ew  = w*64;               // this wave's hidden-col base (GEMM1)

    // ---- register-resident weight B-fragments ----
    bf16x8 w1f[2][4];
    #pragma unroll
    for (int kf = 0; kf < 2; ++kf)
        #pragma unroll
        for (int et = 0; et < 4; ++et)
            #pragma unroll
            for (int ii = 0; ii < 8; ++ii)
                w1f[kf][et][ii] = (__bf16)attn_w1[(kf*32 + lg*8 + ii)*256 + Ew + et*16 + ln];
    bf16x8 w2f[8];
    #pragma unroll
    for (int kf = 0; kf < 8; ++kf)
        #pragma unroll
        for (int ii = 0; ii < 8; ++ii)
            w2f[kf][ii] = (__bf16)attn_w2[(kf*32 + lg*8 + ii)*64 + dch];
    bf16x8 pwf[4][2];                   // all-d pos_w2 B-frags (j-sliced rpe)
    #pragma unroll
    for (int db = 0; db < 4; ++db)
        #pragma unroll
        for (int kf = 0; kf < 2; ++kf)
            #pragma unroll
            for (int ii = 0; ii < 8; ++ii)
                pwf[db][kf][ii] = (__bf16)pos_w2[(kf*32 + lg*8 + ii)*64 + db*16 + ln];

    float b1v[4], qr[4], pb2r[4];
    #pragma unroll
    for (int et = 0; et < 4; ++et) b1v[et] = attn_b1[Ew + et*16 + ln];
    #pragma unroll
    for (int db = 0; db < 4; ++db){
        qr[db]   = qp[blk*64 + db*16 + ln];
        pb2r[db] = pos_b2[db*16 + ln];
    }
    const float b2v  = attn_b2[dch];
    const float qdch = qp[blk*64 + dch];       // q at this lane's channel

    const unsigned sTTb = (unsigned)(unsigned long long)&sTT[0][0][0][0][0];
    const unsigned sHTb = (unsigned)(unsigned long long)&sHT[0][0][0][0];
    const int dq = dch >> 2, dr = dch & 3;     // sTT coords of this channel

    float mrun = -1e30f, srun = 0.f, arun = 0.f;

    // ---- stage A as a reusable block (writes sTT[(j0a/64)&1]) ----
    auto stageA = [&](int j0a){
        const int bufa = (j0a >> 6) & 1;
        // k prefetch for T:  k[j = j0a+w*16+lg*4+ri][t = db*16+ln]
        float kvv[4][4];
        #pragma unroll
        for (int db = 0; db < 4; ++db)
            #pragma unroll
            for (int ri = 0; ri < 4; ++ri)
                kvv[db][ri] = kp[(b*512 + j0a + w*16 + lg*4 + ri)*64 + db*16 + ln];
        // h1 in A-frag layout: lane j = j0a+w*16+ln, h = kf*32+lg*8+ii
        const float* pj = &pos[(b*512 + j0a + w*16 + ln)*3];
        const float r0 = sPOSI[0] - pj[0];
        const float r1 = sPOSI[1] - pj[1];
        const float r2 = sPOSI[2] - pj[2];
        bf16x8 h1f[2];
        #pragma unroll
        for (int kf = 0; kf < 2; ++kf){
            const int hb = kf*32 + lg*8;
            f32x4 wa0 = *(const f32x4*)&sPW1[      hb],   wa1 = *(const f32x4*)&sPW1[      hb+4];
            f32x4 wb0 = *(const f32x4*)&sPW1[ 64 + hb],   wb1 = *(const f32x4*)&sPW1[ 64 + hb+4];
            f32x4 wc0 = *(const f32x4*)&sPW1[128 + hb],   wc1 = *(const f32x4*)&sPW1[128 + hb+4];
            f32x4 bb0 = *(const f32x4*)&sPB1[      hb],   bb1 = *(const f32x4*)&sPB1[      hb+4];
            #pragma unroll
            for (int ii = 0; ii < 4; ++ii){
                float hv0 = bb0[ii] + r0*wa0[ii] + r1*wb0[ii] + r2*wc0[ii];
                float hv1 = bb1[ii] + r0*wa1[ii] + r1*wb1[ii] + r2*wc1[ii];
                h1f[kf][ii]   = (__bf16)fmaxf(hv0, 0.f);
                h1f[kf][ii+4] = (__bf16)fmaxf(hv1, 0.f);
            }
        }
        // rpe = h1 @ pos_w2 + pos_b2  (j-sliced: rows j0a+w*16.., all 64 d)
        f32x4 rpeC[4];
        __builtin_amdgcn_s_setprio(1);
        #pragma unroll
        for (int db = 0; db < 4; ++db){
            f32x4 acc = {pb2r[db], pb2r[db], pb2r[db], pb2r[db]};
            acc = __builtin_amdgcn_mfma_f32_16x16x32_bf16(h1f[0], pwf[db][0], acc, 0, 0, 0);
            acc = __builtin_amdgcn_mfma_f32_16x16x32_bf16(h1f[1], pwf[db][1], acc, 0, 0, 0);
            rpeC[db] = acc;
        }
        __builtin_amdgcn_s_setprio(0);
        // T = rpe + q - k -> sTT   (C-frag: j=w*16+lg*4+ri, t=db*16+ln)
        #pragma unroll
        for (int db = 0; db < 4; ++db){
            bf16x4 tpk;
            #pragma unroll
            for (int ri = 0; ri < 4; ++ri)
                tpk[ri] = (__bf16)(rpeC[db][ri] + qr[db] - kvv[db][ri]);
            *(bf16x4*)&sTT[bufa][db*4 + (ln>>2)][w][ln&3][lg*4] = tpk;
        }
    };

    __syncthreads();
    stageA(0);

    for (int t = 0; t < 8; ++t){
        const int j0  = t << 6;
        const int buf = t & 1;
        __syncthreads();                                    // B1
        // hoisted next-tile stage A: overlaps with GEMM1 below (phase split)
        if (t < 7) stageA(j0 + 64);
        // ================= stage B: GEMM1 ==============================
        #pragma unroll
        for (int jt = 0; jt < 4; ++jt){
            u32x2 t0 = tr_read(sTTb + 2u*(((buf*16 +     2*lg    )*4 + jt)*64) + ln*8);
            u32x2 t1 = tr_read(sTTb + 2u*(((buf*16 +     2*lg + 1)*4 + jt)*64) + ln*8);
            u32x2 t2 = tr_read(sTTb + 2u*(((buf*16 + 8 + 2*lg    )*4 + jt)*64) + ln*8);
            u32x2 t3 = tr_read(sTTb + 2u*(((buf*16 + 8 + 2*lg + 1)*4 + jt)*64) + ln*8);
            asm volatile("s_waitcnt lgkmcnt(2)" ::: "memory");
            __builtin_amdgcn_sched_barrier(0);
            bf16x8 af0 = frag_cat(t0, t1);
            f32x4 accs[4];
            __builtin_amdgcn_s_setprio(1);
            #pragma unroll
            for (int et = 0; et < 4; ++et){
                f32x4 acc = {b1v[et], b1v[et], b1v[et], b1v[et]};
                accs[et] = __builtin_amdgcn_mfma_f32_16x16x32_bf16(af0, w1f[0][et], acc, 0, 0, 0);
            }
            __builtin_amdgcn_s_setprio(0);
            asm volatile("s_waitcnt lgkmcnt(0)" ::: "memory");
            __builtin_amdgcn_sched_barrier(0);
            bf16x8 af1 = frag_cat(t2, t3);
            __builtin_amdgcn_s_setprio(1);
            #pragma unroll
            for (int et = 0; et < 4; ++et)
                accs[et] = __builtin_amdgcn_mfma_f32_16x16x32_bf16(af1, w1f[1][et], accs[et], 0, 0, 0);
            __builtin_amdgcn_s_setprio(0);
            #pragma unroll
            for (int et = 0; et < 4; ++et){
                bf16x4 hp;
                #pragma unroll
                for (int ri = 0; ri < 4; ++ri) hp[ri] = (__bf16)fmaxf(accs[et][ri], 0.f);
                *(bf16x4*)&sHT[w*16 + et*4 + (ln>>2)][jt][ln&3][lg*4] = hp;
            }
        }
        __syncthreads();                                    // B2
        // ================= stage C: GEMM2 + softmax ====================
        // v2 = v + rpe = (v + k - q_dch) + T   (T re-read from sTT)
        float vc[4][4];
        #pragma unroll
        for (int jt = 0; jt < 4; ++jt)
            #pragma unroll
            for (int ri = 0; ri < 4; ++ri){
                const int off = (b*512 + j0 + jt*16 + lg*4 + ri)*64 + dch;
                vc[jt][ri] = vp[off] + kp[off] - qdch;
            }
        #pragma unroll
        for (int jt = 0; jt < 4; ++jt){
            u32x2 hh[16];
            #pragma unroll
            for (int kf = 0; kf < 8; ++kf){
                hh[kf*2]   = tr_read(sHTb + 2u*(((8*kf + 2*lg    )*4 + jt)*64) + ln*8);
                hh[kf*2+1] = tr_read(sHTb + 2u*(((8*kf + 2*lg + 1)*4 + jt)*64) + ln*8);
            }
            bf16x4 tq = *(const bf16x4*)&sTT[buf][dq][jt][dr][lg*4];
            // first 8 tr_reads done (17 lgkm ops outstanding incl tq read)
            asm volatile("s_waitcnt lgkmcnt(9)" ::: "memory");
            __builtin_amdgcn_sched_barrier(0);
            f32x4 acc = {b2v, b2v, b2v, b2v};
            __builtin_amdgcn_s_setprio(1);
            #pragma unroll
            for (int kf = 0; kf < 4; ++kf)
                acc = __builtin_amdgcn_mfma_f32_16x16x32_bf16(frag_cat(hh[kf*2], hh[kf*2+1]), w2f[kf], acc, 0, 0, 0);
            __builtin_amdgcn_s_setprio(0);
            asm volatile("s_waitcnt lgkmcnt(0)" ::: "memory");
            __builtin_amdgcn_sched_barrier(0);
            __builtin_amdgcn_s_setprio(1);
            #pragma unroll
            for (int kf = 4; kf < 8; ++kf)
                acc = __builtin_amdgcn_mfma_f32_16x16x32_bf16(frag_cat(hh[kf*2], hh[kf*2+1]), w2f[kf], acc, 0, 0, 0);
            __builtin_amdgcn_s_setprio(0);
            float tmax = fmaxf(fmaxf(acc[0], acc[1]), fmaxf(acc[2], acc[3]));
            tmax = fmaxf(tmax, __shfl_xor(tmax, 16));
            tmax = fmaxf(tmax, __shfl_xor(tmax, 32));
            const float mnew  = fmaxf(mrun, tmax);
            const float scale = __expf(mrun - mnew);
            srun *= scale; arun *= scale; mrun = mnew;
            #pragma unroll
            for (int ri = 0; ri < 4; ++ri){
                const float p  = __expf(acc[ri] - mnew);
                srun += p;
                arun += p * (vc[jt][ri] + (float)tq[ri]);
            }
        }
        // no tail barrier: sTT double-buffered; sHT WAR covered by next B1
    }

    arun += __shfl_xor(arun, 16); arun += __shfl_xor(arun, 32);
    srun += __shfl_xor(srun, 16); srun += __shfl_xor(srun, 32);
    if (lg == 0) sAGG[dch] = arun / srun;
    __syncthreads();

    if (tid < 64){
        float a = fin_b[tid] + sX1[tid];
        #pragma unroll 16
        for (int c = 0; c < 64; ++c) a += sAGG[c] * fin_w[c*64 + tid];
        out[blk*64 + tid] = a;
    }
}

// ---------------------------------------------------------------------------
extern "C" void kernel_launch(void* const* d_in, const int* in_sizes, int n_in,
                              void* d_out, int out_size, void* d_ws, size_t ws_size,
                              hipStream_t stream)
{
    const float* x       = (const float*)d_in[0];
    const float* pos     = (const float*)d_in[1];
    const float* prev_w  = (const float*)d_in[2];
    const float* prev_b  = (const float*)d_in[3];
    const float* q_w     = (const float*)d_in[4];
    const float* k_w     = (const float*)d_in[5];
    const float* v_w     = (const float*)d_in[6];
    const float* pos_w1  = (const float*)d_in[7];
    const float* pos_b1  = (const float*)d_in[8];
    const float* pos_w2  = (const float*)d_in[9];
    const float* pos_b2  = (const float*)d_in[10];
    const float* attn_w1 = (const float*)d_in[11];
    const float* attn_b1 = (const float*)d_in[12];
    const float* attn_w2 = (const float*)d_in[13];
    const float* attn_b2 = (const float*)d_in[14];
    const float* fin_w   = (const float*)d_in[15];
    const float* fin_b   = (const float*)d_in[16];
    float* out = (float*)d_out;
    float* ws  = (float*)d_ws;

    ptb_precompute<<<1024, 64, 0, stream>>>(x, pos, prev_w, prev_b, q_w, k_w, v_w, ws, out);
    ptb_main<<<1024, 256, 0, stream>>>(pos, pos_w1, pos_b1, pos_w2, pos_b2,
                                       attn_w1, attn_b1, attn_w2, attn_b2,
                                       fin_w, fin_b, ws, out);
}

// Round 4
// 133.385 us; speedup vs baseline: 1.0736x; 1.0736x over previous
//
#include <hip/hip_runtime.h>

typedef __attribute__((ext_vector_type(4))) float f32x4;
typedef __attribute__((ext_vector_type(8))) __bf16 bf16x8;
typedef __attribute__((ext_vector_type(4))) __bf16 bf16x4;
typedef __attribute__((ext_vector_type(2))) unsigned int u32x2;

__device__ __forceinline__ u32x2 tr_read(unsigned int byte_addr){
    u32x2 d;
    asm volatile("ds_read_b64_tr_b16 %0, %1" : "=v"(d) : "v"(byte_addr));
    return d;
}
__device__ __forceinline__ bf16x8 frag_cat(u32x2 a, u32x2 b){
    union { u32x2 u[2]; bf16x8 f; } c; c.u[0] = a; c.u[1] = b; return c.f;
}

// ---------------------------------------------------------------------------
// Kernel A: x1 = x@prev_w+prev_b ; q/k/v = x1@{q,k,v}_w ; pos passthrough out
// ---------------------------------------------------------------------------
__global__ void ptb_precompute(const float* __restrict__ x,
                               const float* __restrict__ pos,
                               const float* __restrict__ prev_w,
                               const float* __restrict__ prev_b,
                               const float* __restrict__ q_w,
                               const float* __restrict__ k_w,
                               const float* __restrict__ v_w,
                               float* __restrict__ ws,
                               float* __restrict__ out)
{
    const int row = blockIdx.x;
    const int d   = threadIdx.x;
    __shared__ float xr[64], x1r[64];
    xr[d] = x[row*64 + d];
    __syncthreads();
    float a = prev_b[d];
    #pragma unroll 16
    for (int c = 0; c < 64; ++c) a += xr[c] * prev_w[c*64 + d];
    x1r[d] = a;
    ws[row*64 + d] = a;
    __syncthreads();
    float qv = 0.f, kv = 0.f, vv = 0.f;
    #pragma unroll 16
    for (int c = 0; c < 64; ++c){
        float t = x1r[c];
        qv += t * q_w[c*64 + d];
        kv += t * k_w[c*64 + d];
        vv += t * v_w[c*64 + d];
    }
    ws[ 65536 + row*64 + d] = qv;
    ws[131072 + row*64 + d] = kv;
    ws[196608 + row*64 + d] = vv;
    const int gid = row*64 + d;
    if (gid < 2*512*3) out[65536 + gid] = pos[gid];
}

// ---------------------------------------------------------------------------
// Kernel B: one block per (b,i). 4 waves. 64-j tiles.
// Pipeline: A(0) ; loop t: { B1 ; A(t+1) ; B(t) ; B2 ; C(t) }
// Round-4: sRT restored (round-1 k-reload cost +6us of VALU+loads);
// stage-C softmax deferred to once per tile (4x shorter serial chain);
// stage-C MFMA chain split into 2 accumulators.
// NO launch-bounds min-waves pin (round-1: forced VGPR 84 + spills).
// ---------------------------------------------------------------------------
__global__ __launch_bounds__(256) void ptb_main(
    const float* __restrict__ pos,
    const float* __restrict__ pos_w1, const float* __restrict__ pos_b1,
    const float* __restrict__ pos_w2, const float* __restrict__ pos_b2,
    const float* __restrict__ attn_w1, const float* __restrict__ attn_b1,
    const float* __restrict__ attn_w2, const float* __restrict__ attn_b2,
    const float* __restrict__ fin_w, const float* __restrict__ fin_b,
    const float* __restrict__ ws, float* __restrict__ out)
{
    const int blk = blockIdx.x;
    const int b   = blk >> 9;
    const int i   = blk & 511;
    const int tid = threadIdx.x;
    const int w   = tid >> 6;
    const int l   = tid & 63;
    const int lg  = l >> 4;
    const int ln  = l & 15;

    // T^T tile, subtiled for tr_read: [buf][es=t/4][jt][er=t&3][jl] bf16
    __shared__ __bf16 sTT[2][16][4][4][16];      // 16 KB
    // H^T tile: [es=e/4][jt][er][jl]
    __shared__ __bf16 sHT[64][4][4][16];         // 32 KB
    // rpe for v2: [buf][d][ j ^ ((d&7)<<3) ]
    __shared__ __bf16 sRT[2][64][64];            // 16 KB
    __shared__ float sPW1[192], sPB1[64], sX1[64], sAGG[64], sPOSI[3];

    const float* x1p = ws;
    const float* qp  = ws + 65536;
    const float* kp  = ws + 131072;
    const float* vp  = ws + 196608;

    if (tid < 64){
        sX1[tid]  = x1p[blk*64 + tid];
        sPB1[tid] = pos_b1[tid];
    }
    if (tid >= 64 && tid < 256) sPW1[tid - 64] = pos_w1[tid - 64];
    if (tid < 3) sPOSI[tid] = pos[(b*512 + i)*3 + tid];

    const int dch = w*16 + ln;          // this lane's output channel (GEMM2)
    const int Ew  = w*64;               // this wave's hidden-col base (GEMM1)

    // ---- register-resident weight B-fragments ----
    bf16x8 w1f[2][4];
    #pragma unroll
    for (int kf = 0; kf < 2; ++kf)
        #pragma unroll
        for (int et = 0; et < 4; ++et)
            #pragma unroll
            for (int ii = 0; ii < 8; ++ii)
                w1f[kf][et][ii] = (__bf16)attn_w1[(kf*32 + lg*8 + ii)*256 + Ew + et*16 + ln];
    bf16x8 w2f[8];
    #pragma unroll
    for (int kf = 0; kf < 8; ++kf)
        #pragma unroll
        for (int ii = 0; ii < 8; ++ii)
            w2f[kf][ii] = (__bf16)attn_w2[(kf*32 + lg*8 + ii)*64 + dch];
    bf16x8 pwf[4][2];                   // all-d pos_w2 B-frags (j-sliced rpe)
    #pragma unroll
    for (int db = 0; db < 4; ++db)
        #pragma unroll
        for (int kf = 0; kf < 2; ++kf)
            #pragma unroll
            for (int ii = 0; ii < 8; ++ii)
                pwf[db][kf][ii] = (__bf16)pos_w2[(kf*32 + lg*8 + ii)*64 + db*16 + ln];

    float b1v[4], qr[4], pb2r[4];
    #pragma unroll
    for (int et = 0; et < 4; ++et) b1v[et] = attn_b1[Ew + et*16 + ln];
    #pragma unroll
    for (int db = 0; db < 4; ++db){
        qr[db]   = qp[blk*64 + db*16 + ln];
        pb2r[db] = pos_b2[db*16 + ln];
    }
    const float b2v = attn_b2[dch];

    const unsigned sTTb = (unsigned)(unsigned long long)&sTT[0][0][0][0][0];
    const unsigned sHTb = (unsigned)(unsigned long long)&sHT[0][0][0][0];

    float mrun = -1e30f, srun = 0.f, arun = 0.f;

    // ---- stage A as a reusable block (writes sTT/sRT buf (j0a/64)&1) ----
    auto stageA = [&](int j0a){
        const int bufa = (j0a >> 6) & 1;
        // k prefetch for T:  k[j = j0a+w*16+lg*4+ri][t = db*16+ln]
        float kvv[4][4];
        #pragma unroll
        for (int db = 0; db < 4; ++db)
            #pragma unroll
            for (int ri = 0; ri < 4; ++ri)
                kvv[db][ri] = kp[(b*512 + j0a + w*16 + lg*4 + ri)*64 + db*16 + ln];
        // h1 in A-frag layout: lane j = j0a+w*16+ln, h = kf*32+lg*8+ii
        const float* pj = &pos[(b*512 + j0a + w*16 + ln)*3];
        const float r0 = sPOSI[0] - pj[0];
        const float r1 = sPOSI[1] - pj[1];
        const float r2 = sPOSI[2] - pj[2];
        bf16x8 h1f[2];
        #pragma unroll
        for (int kf = 0; kf < 2; ++kf){
            const int hb = kf*32 + lg*8;
            f32x4 wa0 = *(const f32x4*)&sPW1[      hb],   wa1 = *(const f32x4*)&sPW1[      hb+4];
            f32x4 wb0 = *(const f32x4*)&sPW1[ 64 + hb],   wb1 = *(const f32x4*)&sPW1[ 64 + hb+4];
            f32x4 wc0 = *(const f32x4*)&sPW1[128 + hb],   wc1 = *(const f32x4*)&sPW1[128 + hb+4];
            f32x4 bb0 = *(const f32x4*)&sPB1[      hb],   bb1 = *(const f32x4*)&sPB1[      hb+4];
            #pragma unroll
            for (int ii = 0; ii < 4; ++ii){
                float hv0 = bb0[ii] + r0*wa0[ii] + r1*wb0[ii] + r2*wc0[ii];
                float hv1 = bb1[ii] + r0*wa1[ii] + r1*wb1[ii] + r2*wc1[ii];
                h1f[kf][ii]   = (__bf16)fmaxf(hv0, 0.f);
                h1f[kf][ii+4] = (__bf16)fmaxf(hv1, 0.f);
            }
        }
        // rpe = h1 @ pos_w2 + pos_b2  (j-sliced: rows j0a+w*16.., all 64 d)
        f32x4 rpeC[4];
        __builtin_amdgcn_s_setprio(1);
        #pragma unroll
        for (int db = 0; db < 4; ++db){
            f32x4 acc = {pb2r[db], pb2r[db], pb2r[db], pb2r[db]};
            acc = __builtin_amdgcn_mfma_f32_16x16x32_bf16(h1f[0], pwf[db][0], acc, 0, 0, 0);
            acc = __builtin_amdgcn_mfma_f32_16x16x32_bf16(h1f[1], pwf[db][1], acc, 0, 0, 0);
            rpeC[db] = acc;
        }
        __builtin_amdgcn_s_setprio(0);
        // T = rpe + q - k -> sTT ; raw rpe -> sRT (C-frag: j=w*16+lg*4+ri)
        #pragma unroll
        for (int db = 0; db < 4; ++db){
            bf16x4 tpk, rpk;
            #pragma unroll
            for (int ri = 0; ri < 4; ++ri){
                tpk[ri] = (__bf16)(rpeC[db][ri] + qr[db] - kvv[db][ri]);
                rpk[ri] = (__bf16)rpeC[db][ri];
            }
            *(bf16x4*)&sTT[bufa][db*4 + (ln>>2)][w][ln&3][lg*4] = tpk;
            *(bf16x4*)&sRT[bufa][db*16 + ln][(w*16 + lg*4) ^ ((ln&7)<<3)] = rpk;
        }
    };

    __syncthreads();
    stageA(0);

    for (int t = 0; t < 8; ++t){
        const int j0  = t << 6;
        const int buf = t & 1;
        __syncthreads();                                    // B1
        // hoisted next-tile stage A: overlaps with GEMM1 below (phase split)
        if (t < 7) stageA(j0 + 64);
        // ================= stage B: GEMM1 ==============================
        #pragma unroll
        for (int jt = 0; jt < 4; ++jt){
            u32x2 t0 = tr_read(sTTb + 2u*(((buf*16 +     2*lg    )*4 + jt)*64) + ln*8);
            u32x2 t1 = tr_read(sTTb + 2u*(((buf*16 +     2*lg + 1)*4 + jt)*64) + ln*8);
            u32x2 t2 = tr_read(sTTb + 2u*(((buf*16 + 8 + 2*lg    )*4 + jt)*64) + ln*8);
            u32x2 t3 = tr_read(sTTb + 2u*(((buf*16 + 8 + 2*lg + 1)*4 + jt)*64) + ln*8);
            asm volatile("s_waitcnt lgkmcnt(2)" ::: "memory");
            __builtin_amdgcn_sched_barrier(0);
            bf16x8 af0 = frag_cat(t0, t1);
            f32x4 accs[4];
            __builtin_amdgcn_s_setprio(1);
            #pragma unroll
            for (int et = 0; et < 4; ++et){
                f32x4 acc = {b1v[et], b1v[et], b1v[et], b1v[et]};
                accs[et] = __builtin_amdgcn_mfma_f32_16x16x32_bf16(af0, w1f[0][et], acc, 0, 0, 0);
            }
            __builtin_amdgcn_s_setprio(0);
            asm volatile("s_waitcnt lgkmcnt(0)" ::: "memory");
            __builtin_amdgcn_sched_barrier(0);
            bf16x8 af1 = frag_cat(t2, t3);
            __builtin_amdgcn_s_setprio(1);
            #pragma unroll
            for (int et = 0; et < 4; ++et)
                accs[et] = __builtin_amdgcn_mfma_f32_16x16x32_bf16(af1, w1f[1][et], accs[et], 0, 0, 0);
            __builtin_amdgcn_s_setprio(0);
            #pragma unroll
            for (int et = 0; et < 4; ++et){
                bf16x4 hp;
                #pragma unroll
                for (int ri = 0; ri < 4; ++ri) hp[ri] = (__bf16)fmaxf(accs[et][ri], 0.f);
                *(bf16x4*)&sHT[w*16 + et*4 + (ln>>2)][jt][ln&3][lg*4] = hp;
            }
        }
        __syncthreads();                                    // B2
        // ================= stage C: GEMM2 + deferred softmax ===========
        float vv[4][4];
        #pragma unroll
        for (int jt = 0; jt < 4; ++jt)
            #pragma unroll
            for (int ri = 0; ri < 4; ++ri)
                vv[jt][ri] = vp[(b*512 + j0 + jt*16 + lg*4 + ri)*64 + dch];
        f32x4 accs[4];
        bf16x4 rpks[4];
        #pragma unroll
        for (int jt = 0; jt < 4; ++jt){
            u32x2 hh[16];
            #pragma unroll
            for (int kf = 0; kf < 8; ++kf){
                hh[kf*2]   = tr_read(sHTb + 2u*(((8*kf + 2*lg    )*4 + jt)*64) + ln*8);
                hh[kf*2+1] = tr_read(sHTb + 2u*(((8*kf + 2*lg + 1)*4 + jt)*64) + ln*8);
            }
            rpks[jt] = *(const bf16x4*)&sRT[buf][dch][(jt*16 + lg*4) ^ ((ln&7)<<3)];
            asm volatile("s_waitcnt lgkmcnt(0)" ::: "memory");
            __builtin_amdgcn_sched_barrier(0);
            f32x4 a0 = {b2v, b2v, b2v, b2v};
            f32x4 a1 = {0.f, 0.f, 0.f, 0.f};
            __builtin_amdgcn_s_setprio(1);
            #pragma unroll
            for (int kf = 0; kf < 4; ++kf){
                a0 = __builtin_amdgcn_mfma_f32_16x16x32_bf16(frag_cat(hh[kf*2],   hh[kf*2+1]),   w2f[kf],   a0, 0, 0, 0);
                a1 = __builtin_amdgcn_mfma_f32_16x16x32_bf16(frag_cat(hh[kf*2+8], hh[kf*2+9]),   w2f[kf+4], a1, 0, 0, 0);
            }
            __builtin_amdgcn_s_setprio(0);
            accs[jt] = a0 + a1;
        }
        // one deferred softmax update per 64-j tile
        float tmax = -1e30f;
        #pragma unroll
        for (int jt = 0; jt < 4; ++jt)
            tmax = fmaxf(tmax, fmaxf(fmaxf(accs[jt][0], accs[jt][1]),
                                     fmaxf(accs[jt][2], accs[jt][3])));
        tmax = fmaxf(tmax, __shfl_xor(tmax, 16));
        tmax = fmaxf(tmax, __shfl_xor(tmax, 32));
        const float mnew  = fmaxf(mrun, tmax);
        const float scale = __expf(mrun - mnew);
        srun *= scale; arun *= scale; mrun = mnew;
        #pragma unroll
        for (int jt = 0; jt < 4; ++jt)
            #pragma unroll
            for (int ri = 0; ri < 4; ++ri){
                const float p = __expf(accs[jt][ri] - mnew);
                srun += p;
                arun += p * (vv[jt][ri] + (float)rpks[jt][ri]);
            }
        // no tail barrier: sTT/sRT double-buffered; sHT WAR covered by next B1
    }

    arun += __shfl_xor(arun, 16); arun += __shfl_xor(arun, 32);
    srun += __shfl_xor(srun, 16); srun += __shfl_xor(srun, 32);
    if (lg == 0) sAGG[dch] = arun / srun;
    __syncthreads();

    if (tid < 64){
        float a = fin_b[tid] + sX1[tid];
        #pragma unroll 16
        for (int c = 0; c < 64; ++c) a += sAGG[c] * fin_w[c*64 + tid];
        out[blk*64 + tid] = a;
    }
}

// ---------------------------------------------------------------------------
extern "C" void kernel_launch(void* const* d_in, const int* in_sizes, int n_in,
                              void* d_out, int out_size, void* d_ws, size_t ws_size,
                              hipStream_t stream)
{
    const float* x       = (const float*)d_in[0];
    const float* pos     = (const float*)d_in[1];
    const float* prev_w  = (const float*)d_in[2];
    const float* prev_b  = (const float*)d_in[3];
    const float* q_w     = (const float*)d_in[4];
    const float* k_w     = (const float*)d_in[5];
    const float* v_w     = (const float*)d_in[6];
    const float* pos_w1  = (const float*)d_in[7];
    const float* pos_b1  = (const float*)d_in[8];
    const float* pos_w2  = (const float*)d_in[9];
    const float* pos_b2  = (const float*)d_in[10];
    const float* attn_w1 = (const float*)d_in[11];
    const float* attn_b1 = (const float*)d_in[12];
    const float* attn_w2 = (const float*)d_in[13];
    const float* attn_b2 = (const float*)d_in[14];
    const float* fin_w   = (const float*)d_in[15];
    const float* fin_b   = (const float*)d_in[16];
    float* out = (float*)d_out;
    float* ws  = (float*)d_ws;

    ptb_precompute<<<1024, 64, 0, stream>>>(x, pos, prev_w, prev_b, q_w, k_w, v_w, ws, out);
    ptb_main<<<1024, 256, 0, stream>>>(pos, pos_w1, pos_b1, pos_w2, pos_b2,
                                       attn_w1, attn_b1, attn_w2, attn_b2,
                                       fin_w, fin_b, ws, out);
}